// Round 1
// baseline (368.204 us; speedup 1.0000x reference)
//
#include <hip/hip_runtime.h>
#include <hip/hip_fp16.h>

// Problem constants
#define HIDDEN 1024
#define HEADS  16
#define DH     64
#define B_     2
#define L_     2048
#define M_TOT  (B_ * L_)          // 4096 rows in all projections
#define ELEMS  (M_TOT * HIDDEN)   // 4,194,304 per activation tensor

typedef _Float16 f16;
typedef _Float16 f16x8 __attribute__((ext_vector_type(8)));
typedef float    f32x4 __attribute__((ext_vector_type(4)));

// ---------------------------------------------------------------------------
// GEMM-NT helper notes (mfma_f32_16x16x32_f16, verified layouts from guide):
//   A-frag: lane holds A[m = lane&15][k = (lane>>4)*8 + j], j=0..7  (16B)
//   B-frag: lane holds B[k = (lane>>4)*8 + j][n = lane&15]          (16B)
//           -> for C = A @ W^T (W row-major [N,K]) B-frag is 8 contiguous
//              K-elements of W row n. Both operands: row = lane&15, 8 contig K.
//   C/D:    lane,reg -> row m = (lane>>4)*4 + reg, col n = lane&15
// ---------------------------------------------------------------------------

// Fused QKV projection: C = query @ W{q,k,v}^T + b, output f16 in [B,H,L,64].
// grid.x = M/64 (=64), grid.y = 48 (16 n-blocks x 3 matrices). block = 256.
__global__ __launch_bounds__(256)
void proj_qkv(const float* __restrict__ A,
              const float* __restrict__ Wq, const float* __restrict__ Wk,
              const float* __restrict__ Wv,
              const float* __restrict__ bq, const float* __restrict__ bk,
              const float* __restrict__ bv,
              f16* __restrict__ Qo, f16* __restrict__ Ko, f16* __restrict__ Vo)
{
    __shared__ f16 As[64][40];   // pad 32->40 halfs: b128 reads 2-way max (free)
    __shared__ f16 Ws[64][40];

    const int tid  = threadIdx.x;
    const int lane = tid & 63;
    const int wave = tid >> 6;
    const int quad = lane >> 4;
    const int l16  = lane & 15;

    const int mb   = blockIdx.x * 64;
    const int nsel = blockIdx.y / 16;            // 0=Q 1=K 2=V
    const int nb   = (blockIdx.y % 16) * 64;

    const float* W    = (nsel == 0) ? Wq : (nsel == 1) ? Wk : Wv;
    const float* bias = (nsel == 0) ? bq : (nsel == 1) ? bk : bv;
    f16*         out  = (nsel == 0) ? Qo : (nsel == 1) ? Ko : Vo;
    const float scale = (nsel == 0) ? 0.125f : 1.0f;   // d_head^-0.5 on Q

    const int srow = tid >> 2;         // 0..63
    const int scol = (tid & 3) * 8;    // 0,8,16,24

    const int wm = (wave >> 1) * 32;
    const int wn = (wave & 1) * 32;

    f32x4 acc[2][2] = {};

    for (int kb = 0; kb < HIDDEN; kb += 32) {
        const float4 a0 = *(const float4*)&A[(mb + srow) * HIDDEN + kb + scol];
        const float4 a1 = *(const float4*)&A[(mb + srow) * HIDDEN + kb + scol + 4];
        const float4 w0 = *(const float4*)&W[(nb + srow) * HIDDEN + kb + scol];
        const float4 w1 = *(const float4*)&W[(nb + srow) * HIDDEN + kb + scol + 4];
        f16x8 av = { (f16)a0.x, (f16)a0.y, (f16)a0.z, (f16)a0.w,
                     (f16)a1.x, (f16)a1.y, (f16)a1.z, (f16)a1.w };
        f16x8 wv = { (f16)w0.x, (f16)w0.y, (f16)w0.z, (f16)w0.w,
                     (f16)w1.x, (f16)w1.y, (f16)w1.z, (f16)w1.w };
        *(f16x8*)&As[srow][scol] = av;
        *(f16x8*)&Ws[srow][scol] = wv;
        __syncthreads();

        f16x8 af[2], bf[2];
        af[0] = *(const f16x8*)&As[wm + l16][quad * 8];
        af[1] = *(const f16x8*)&As[wm + 16 + l16][quad * 8];
        bf[0] = *(const f16x8*)&Ws[wn + l16][quad * 8];
        bf[1] = *(const f16x8*)&Ws[wn + 16 + l16][quad * 8];
#pragma unroll
        for (int i = 0; i < 2; i++)
#pragma unroll
            for (int j = 0; j < 2; j++)
                acc[i][j] = __builtin_amdgcn_mfma_f32_16x16x32_f16(af[i], bf[j], acc[i][j], 0, 0, 0);
        __syncthreads();
    }

#pragma unroll
    for (int i = 0; i < 2; i++)
#pragma unroll
        for (int j = 0; j < 2; j++) {
            const int n  = nb + wn + j * 16 + l16;
            const float bn = bias[n];
            const int h  = n >> 6, dd = n & 63;
#pragma unroll
            for (int r = 0; r < 4; r++) {
                const int m = mb + wm + i * 16 + quad * 4 + r;
                const int b = m >> 11, l = m & (L_ - 1);
                const float val = (acc[i][j][r] + bn) * scale;
                out[(((b * HEADS + h) * L_) + l) * DH + dd] = (f16)val;
            }
        }
}

// Output projection: d_out = X @ Wo^T + bo, X f16 [B*L, 1024], out f32.
__global__ __launch_bounds__(256)
void proj_out(const f16* __restrict__ X, const float* __restrict__ Wo,
              const float* __restrict__ bo, float* __restrict__ out)
{
    __shared__ f16 As[64][40];
    __shared__ f16 Ws[64][40];

    const int tid  = threadIdx.x;
    const int lane = tid & 63;
    const int wave = tid >> 6;
    const int quad = lane >> 4;
    const int l16  = lane & 15;

    const int mb = blockIdx.x * 64;
    const int nb = blockIdx.y * 64;

    const int srow = tid >> 2;
    const int scol = (tid & 3) * 8;

    const int wm = (wave >> 1) * 32;
    const int wn = (wave & 1) * 32;

    f32x4 acc[2][2] = {};

    for (int kb = 0; kb < HIDDEN; kb += 32) {
        f16x8 av = *(const f16x8*)&X[(mb + srow) * HIDDEN + kb + scol];
        const float4 w0 = *(const float4*)&Wo[(nb + srow) * HIDDEN + kb + scol];
        const float4 w1 = *(const float4*)&Wo[(nb + srow) * HIDDEN + kb + scol + 4];
        f16x8 wv = { (f16)w0.x, (f16)w0.y, (f16)w0.z, (f16)w0.w,
                     (f16)w1.x, (f16)w1.y, (f16)w1.z, (f16)w1.w };
        *(f16x8*)&As[srow][scol] = av;
        *(f16x8*)&Ws[srow][scol] = wv;
        __syncthreads();

        f16x8 af[2], bf[2];
        af[0] = *(const f16x8*)&As[wm + l16][quad * 8];
        af[1] = *(const f16x8*)&As[wm + 16 + l16][quad * 8];
        bf[0] = *(const f16x8*)&Ws[wn + l16][quad * 8];
        bf[1] = *(const f16x8*)&Ws[wn + 16 + l16][quad * 8];
#pragma unroll
        for (int i = 0; i < 2; i++)
#pragma unroll
            for (int j = 0; j < 2; j++)
                acc[i][j] = __builtin_amdgcn_mfma_f32_16x16x32_f16(af[i], bf[j], acc[i][j], 0, 0, 0);
        __syncthreads();
    }

#pragma unroll
    for (int i = 0; i < 2; i++)
#pragma unroll
        for (int j = 0; j < 2; j++) {
            const int n = nb + wn + j * 16 + l16;
            const float bn = bo[n];
#pragma unroll
            for (int r = 0; r < 4; r++) {
                const int m = mb + wm + i * 16 + quad * 4 + r;
                out[m * HIDDEN + n] = acc[i][j][r] + bn;
            }
        }
}

// Flash attention: one wave per 16-row Q tile, 32-key steps, online softmax.
// Q,K,V f16 [B,H,L,64] (Q pre-scaled); bias f32 [B,L]; X f16 [B,L,1024].
// grid = 1024 blocks of 256 (4 waves); block handles 4 Q-tiles of one (b,h).
__global__ __launch_bounds__(256)
void attn(const f16* __restrict__ Q, const f16* __restrict__ K,
          const f16* __restrict__ V, const float* __restrict__ bias,
          f16* __restrict__ X)
{
    __shared__ f16 ptile[4][16][40];   // per-wave private P tile, padded

    const int tid  = threadIdx.x;
    const int lane = tid & 63;
    const int wave = tid >> 6;
    const int quad = lane >> 4;
    const int l16  = lane & 15;

    const int bh = blockIdx.x >> 5;            // 0..31
    const int b  = bh >> 4, h = bh & 15;
    const int qt = (blockIdx.x & 31) * 4 + wave;  // Q tile 0..127

    const f16* Qh = Q + (size_t)bh * L_ * DH;
    const f16* Kh = K + (size_t)bh * L_ * DH;
    const f16* Vh = V + (size_t)bh * L_ * DH;
    const float* biasb = bias + b * L_;

    f16x8 qf[2];
    qf[0] = *(const f16x8*)&Qh[(qt * 16 + l16) * DH + quad * 8];
    qf[1] = *(const f16x8*)&Qh[(qt * 16 + l16) * DH + 32 + quad * 8];

    f32x4 o[4] = {};
    float mrow[4] = { -INFINITY, -INFINITY, -INFINITY, -INFINITY };
    float lrow[4] = {};

    for (int kb = 0; kb < L_; kb += 32) {
        // S tile 16x32: rows = this wave's 16 queries, cols = 32 keys
        f32x4 s0 = {}, s1 = {};
        {
            f16x8 kf;
            kf = *(const f16x8*)&Kh[(kb + l16) * DH + quad * 8];
            s0 = __builtin_amdgcn_mfma_f32_16x16x32_f16(qf[0], kf, s0, 0, 0, 0);
            kf = *(const f16x8*)&Kh[(kb + l16) * DH + 32 + quad * 8];
            s0 = __builtin_amdgcn_mfma_f32_16x16x32_f16(qf[1], kf, s0, 0, 0, 0);
            kf = *(const f16x8*)&Kh[(kb + 16 + l16) * DH + quad * 8];
            s1 = __builtin_amdgcn_mfma_f32_16x16x32_f16(qf[0], kf, s1, 0, 0, 0);
            kf = *(const f16x8*)&Kh[(kb + 16 + l16) * DH + 32 + quad * 8];
            s1 = __builtin_amdgcn_mfma_f32_16x16x32_f16(qf[1], kf, s1, 0, 0, 0);
        }
        const float bias0 = biasb[kb + l16];
        const float bias1 = biasb[kb + 16 + l16];

        float rmax[4], p0[4], p1[4], rsum[4], alpha[4];
#pragma unroll
        for (int r = 0; r < 4; r++) {
            s0[r] += bias0; s1[r] += bias1;
            rmax[r] = fmaxf(s0[r], s1[r]);
        }
        // reduce over the 16 lanes holding one row (lanes differing in bits 0..3)
#pragma unroll
        for (int x = 1; x < 16; x <<= 1)
#pragma unroll
            for (int r = 0; r < 4; r++)
                rmax[r] = fmaxf(rmax[r], __shfl_xor(rmax[r], x));
#pragma unroll
        for (int r = 0; r < 4; r++) {
            const float mn = fmaxf(mrow[r], rmax[r]);
            alpha[r] = __expf(mrow[r] - mn);
            mrow[r]  = mn;
            p0[r] = __expf(s0[r] - mn);
            p1[r] = __expf(s1[r] - mn);
            rsum[r] = p0[r] + p1[r];
        }
#pragma unroll
        for (int x = 1; x < 16; x <<= 1)
#pragma unroll
            for (int r = 0; r < 4; r++)
                rsum[r] += __shfl_xor(rsum[r], x);
#pragma unroll
        for (int r = 0; r < 4; r++)
            lrow[r] = lrow[r] * alpha[r] + rsum[r];
#pragma unroll
        for (int t = 0; t < 4; t++)
#pragma unroll
            for (int r = 0; r < 4; r++)
                o[t][r] *= alpha[r];

        // P (C-layout) -> LDS row-major [16][32] so it can re-enter as A-frag
#pragma unroll
        for (int r = 0; r < 4; r++) {
            ptile[wave][quad * 4 + r][l16]      = (f16)p0[r];
            ptile[wave][quad * 4 + r][16 + l16] = (f16)p1[r];
        }
        __syncthreads();   // uniform trip count; intra-wave LDS w->r ordering

        const f16x8 pa = *(const f16x8*)&ptile[wave][l16][quad * 8];

        // O += P @ V : B-frag gathers V[kb + k][dd]; tile is cache-hot
#pragma unroll
        for (int t = 0; t < 4; t++) {
            const int dd = t * 16 + l16;
            f16x8 vf;
#pragma unroll
            for (int jj = 0; jj < 8; jj++)
                vf[jj] = Vh[(kb + quad * 8 + jj) * DH + dd];
            o[t] = __builtin_amdgcn_mfma_f32_16x16x32_f16(pa, vf, o[t], 0, 0, 0);
        }
    }

    float inv[4];
#pragma unroll
    for (int r = 0; r < 4; r++) inv[r] = 1.0f / lrow[r];

#pragma unroll
    for (int t = 0; t < 4; t++)
#pragma unroll
        for (int r = 0; r < 4; r++) {
            const int qrow = qt * 16 + quad * 4 + r;
            X[((size_t)b * L_ + qrow) * HIDDEN + h * DH + t * 16 + l16] =
                (f16)(o[t][r] * inv[r]);
        }
}

extern "C" void kernel_launch(void* const* d_in, const int* in_sizes, int n_in,
                              void* d_out, int out_size, void* d_ws, size_t ws_size,
                              hipStream_t stream)
{
    const float* query = (const float*)d_in[0];
    const float* bias  = (const float*)d_in[1];
    const float* Wq = (const float*)d_in[2]; const float* bq = (const float*)d_in[3];
    const float* Wk = (const float*)d_in[4]; const float* bk = (const float*)d_in[5];
    const float* Wv = (const float*)d_in[6]; const float* bv = (const float*)d_in[7];
    const float* Wo = (const float*)d_in[8]; const float* bo = (const float*)d_in[9];
    float* out = (float*)d_out;

    f16* Qf = (f16*)d_ws;          // [B,H,L,64] pre-scaled
    f16* Kf = Qf + ELEMS;          // [B,H,L,64]
    f16* Vf = Kf + ELEMS;          // [B,H,L,64]
    f16* Xf = Vf + ELEMS;          // [B,L,1024] merged heads
    // total workspace: 4 * 8 MiB = 32 MiB

    proj_qkv<<<dim3(64, 48), 256, 0, stream>>>(query, Wq, Wk, Wv, bq, bk, bv, Qf, Kf, Vf);
    attn<<<dim3(1024), 256, 0, stream>>>(Qf, Kf, Vf, bias, Xf);
    proj_out<<<dim3(64, 16), 256, 0, stream>>>(Xf, Wo, bo, out);
}